// Round 3
// baseline (114.966 us; speedup 1.0000x reference)
//
#include <hip/hip_runtime.h>
#include <hip/hip_bf16.h>

#define NLB 4096
#define NULB 6144
#define NROWS 16384   // 4096 + 2*6144
#define DD 128
#define NC 10
#define VW 12                // partial-slab row width: 10 numerators + denom + zero pad
#define SEG 16               // j-segments: grid (64,16)=1024 = 4 blocks/CU, no tail
#define JSEG (NROWS / SEG)   // 1024
#define NTILE (JSEG / 64)    // 16 tiles per segment
#define BI 256               // i-rows per block (4 waves x 64)
#define BJ 64                // j-rows per LDS tile: LDS 20480 B
#define SQRTC 1.6986437f     // sqrt(2*log2(e))

typedef __bf16 bf16_t;
typedef _Float16 f16_t;
typedef f16_t f16x8 __attribute__((ext_vector_type(8)));
typedef float f32x4 __attribute__((ext_vector_type(4)));
typedef short i16x2 __attribute__((ext_vector_type(2)));
typedef int i32x8 __attribute__((ext_vector_type(8)));
typedef unsigned int u32;
typedef unsigned char u8;

// fp8 F global layout = swizzled LDS image, 128-row tiles of 128-byte rows:
//   byte address(row, 16B-chunk c0..7) =
//     (row>>7)*16384 + (row&127)*128 + ((c ^ (row&7)) << 4)
__device__ __forceinline__ size_t f8idx(int row, int c) {
  return ((size_t)(row >> 7) << 14) + (size_t)((row & 127) << 7)
       + (size_t)(((c ^ (row & 7)) & 7) << 4);
}

// pack two f16(2^(c/256)) into one dword (fma + pknorm per pair).
// f16 bits of 2^x ~= round(1024x + 15315.35); x = c/256 -> 4*c.
// pknorm: i16 = round(y*32767) -> y = c*(4/32767) + 15315.35/32767.
// staircase rel err ~0.2%, mean-zero, common-mode num/denom.
__device__ __forceinline__ u32 packexp2f16(float c0, float c1) {
#if __has_builtin(__builtin_amdgcn_cvt_pknorm_i16)
  float y0 = fmaf(c0, 1.2207465e-4f, 0.46740490f);
  float y1 = fmaf(c1, 1.2207465e-4f, 0.46740490f);
  union { i16x2 p; u32 u; } cv;
  cv.p = __builtin_amdgcn_cvt_pknorm_i16(y0, y1);
  return cv.u;
#else
  u32 b0 = (u32)(int)fmaf(c0, 4.0f, 15315.354f);
  u32 b1 = (u32)(int)fmaf(c1, 4.0f, 15315.354f);
  return __builtin_amdgcn_perm(b1, b0, 0x05040100u);
#endif
}

// ================= fused prep =================
// blocks 0..1023   : L2-normalize 16 rows each of [lb;anchor;pos], scale by
//                    16*SQRTC, fp8 e4m3 into swizzled F image.
// blocks 1024..1087: build f16 V fragments (32-row pair-groups) + per-block
//                    class-count partials.
// VF layout: pair-group G (32 j-rows), lane l=(q=l>>4, n=l&15), 16B chunk:
//   f16 V[G*32 + q*4 + d][n] d=0..3, then f16 V[G*32+16 + q*4 + d][n] d=0..3
//   == f16 PV B-frag with k=q*8+{0..3} = even 16-chunk, {4..7} = odd.
__global__ void kprep2(const float* __restrict__ lb, const float* __restrict__ an,
                       const float* __restrict__ po, const float* __restrict__ onehot,
                       const float* __restrict__ l1, const float* __restrict__ l2,
                       u8* __restrict__ F8, f16_t* __restrict__ VF,
                       float* __restrict__ clsPart) {
  __shared__ float Vtmp[256 * 16];
  __shared__ float lcnt[NC];
  int b = blockIdx.x;
  int t = threadIdx.x;

  if (b < 1024) {
    int row = b * 16 + (t >> 4);
    int c = t & 15;           // lane's 8 floats = k bytes c*8 .. c*8+7
    const float* src;
    if (row < NLB) src = lb + (size_t)row * DD;
    else if (row < NLB + NULB) src = an + (size_t)(row - NLB) * DD;
    else src = po + (size_t)(row - NLB - NULB) * DD;
    float4 v0 = ((const float4*)src)[c * 2];
    float4 v1 = ((const float4*)src)[c * 2 + 1];
    float ss = v0.x*v0.x + v0.y*v0.y + v0.z*v0.z + v0.w*v0.w
             + v1.x*v1.x + v1.y*v1.y + v1.z*v1.z + v1.w*v1.w;
#pragma unroll
    for (int off = 8; off >= 1; off >>= 1) ss += __shfl_xor(ss, off);
    float inv = (16.0f * SQRTC) / fmaxf(sqrtf(ss), 1e-12f);
    u32 d0 = (u32)__builtin_amdgcn_cvt_pk_fp8_f32(v0.x*inv, v0.y*inv, 0, false);
    d0 = (u32)__builtin_amdgcn_cvt_pk_fp8_f32(v0.z*inv, v0.w*inv, d0, true);
    u32 d1 = (u32)__builtin_amdgcn_cvt_pk_fp8_f32(v1.x*inv, v1.y*inv, 0, false);
    d1 = (u32)__builtin_amdgcn_cvt_pk_fp8_f32(v1.z*inv, v1.w*inv, d1, true);
    uint2 dd = {d0, d1};
    *(uint2*)(F8 + f8idx(row, c >> 1) + ((c & 1) << 3)) = dd;
    return;
  }

  // ---- V build: 256 rows/block over all 16384 output rows ----
  if (t < NC) lcnt[t] = 0.0f;
  __syncthreads();
  int gid = (b - 1024) * 256 + t;
  float p[16];
  p[10] = 1.0f; p[11] = 0.f; p[12] = 0.f; p[13] = 0.f; p[14] = 0.f; p[15] = 0.f;
  if (gid < NLB) {
    int idx = 0;
#pragma unroll
    for (int c = 0; c < NC; ++c) {
      p[c] = onehot[(size_t)gid * NC + c];
      if (p[c] == 1.0f) idx = c;
    }
    atomicAdd(&lcnt[idx], 1.0f);
  } else {
    int r = (gid < NLB + NULB) ? (gid - NLB) : (gid - NLB - NULB);
    bool count = (gid < NLB + NULB);
    float a[NC], bb[NC];
#pragma unroll
    for (int c = 0; c < NC; ++c) { a[c] = l1[(size_t)r * NC + c]; bb[c] = l2[(size_t)r * NC + c]; }
    float m1 = a[0], m2 = bb[0];
#pragma unroll
    for (int c = 1; c < NC; ++c) { m1 = fmaxf(m1, a[c]); m2 = fmaxf(m2, bb[c]); }
    float s1 = 0.0f, s2 = 0.0f;
#pragma unroll
    for (int c = 0; c < NC; ++c) {
      s1 += expf(2.0f * (a[c] - m1));
      s2 += expf(2.0f * (bb[c] - m2));
    }
    bool take1 = (s1 <= s2);  // max(prob1)=1/s1 >= 1/s2=max(prob2)
    float g[NC];
#pragma unroll
    for (int c = 0; c < NC; ++c) g[c] = take1 ? a[c] : bb[c];
    float mg = g[0];
#pragma unroll
    for (int c = 1; c < NC; ++c) mg = fmaxf(mg, g[c]);
    float e[NC]; float sg = 0.0f;
#pragma unroll
    for (int c = 0; c < NC; ++c) { e[c] = expf(g[c] - mg); sg += e[c]; }
    float msk[NC];
#pragma unroll
    for (int c = 0; c < NC; ++c) msk[c] = ((e[c] / sg) >= 0.95f) ? g[c] : 0.0f;
    float mx = msk[0]; int mi = 0;
#pragma unroll
    for (int c = 1; c < NC; ++c) if (msk[c] > mx) { mx = msk[c]; mi = c; }
    if (count && mx != 0.0f) atomicAdd(&lcnt[mi], 2.0f);
    float mm = 2.0f * msk[0];
#pragma unroll
    for (int c = 1; c < NC; ++c) mm = fmaxf(mm, 2.0f * msk[c]);
    float q[NC]; float sp = 0.0f;
#pragma unroll
    for (int c = 0; c < NC; ++c) { q[c] = expf(2.0f * msk[c] - mm); sp += q[c]; }
#pragma unroll
    for (int c = 0; c < NC; ++c) p[c] = q[c] / sp;
  }
#pragma unroll
  for (int c = 0; c < 16; ++c) Vtmp[t * 16 + c] = p[c];
  __syncthreads();
  if (t < 16) clsPart[(size_t)(b - 1024) * 16 + t] = (t < NC) ? lcnt[t] : 0.0f;
  // scatter to VF f16 pair-frag layout: 512 16B chunks/block, 2 per thread
  int gbase = (b - 1024) * 8;   // 8 pair-groups of 32 rows per 256-row block
#pragma unroll
  for (int u = 0; u < 2; ++u) {
    int cid = u * 256 + t;       // 0..511
    int G = cid >> 6;            // local pair-group 0..7
    int l = cid & 63;
    int q = l >> 4;
    int n = l & 15;
    union { f16_t h[8]; uint4 uu; } pk;
#pragma unroll
    for (int d = 0; d < 4; ++d) {
      pk.h[d]     = (f16_t)Vtmp[(G * 32      + q * 4 + d) * 16 + n];
      pk.h[4 + d] = (f16_t)Vtmp[(G * 32 + 16 + q * 4 + d) * 16 + n];
    }
    *(uint4*)(VF + ((size_t)(gbase + G) * 64 + l) * 8) = pk.uu;
  }
}

// ================= attention partials =================
// R15: per-wave ILP attack. R12->R14 doubled waves/SIMD (2.3->4) for only ~8%
// => wave-level latency hiding is saturated; the limiter is the per-wave RAW
// chain QK -> pack (reads MFMA dest ~100cy later) -> PV (reads VALU results),
// with all 4 waves barrier-locked into the same phase so they stall TOGETHER
// (~2000 unaccounted cyc/tile; MfmaUtil 37 + VALUBusy 33 + LDS 8 = 78%,
// pipes serializing). Two levers the compiler won't apply itself:
//   1. depth-2 s-pipeline: QK(s+1) issues in source order BEFORE pack(s)/PV(s)
//      -> pack reads results that are a full iteration old. +16 VGPR (cap 128).
//   2. s_setprio(1) around MFMA issues, (0) during pack (T5) -> waves in MFMA
//      phase win issue arbitration over waves in VALU phase.
// Everything else unchanged from R14 (slab epilogue, SEG=16, BJ=64, dbuf).
__launch_bounds__(256, 4)
__global__ void kattn(const u8* __restrict__ F8, const f16_t* __restrict__ VF,
                      float* __restrict__ Ppart) {
  __shared__ __align__(16) u8 Fs[2][BJ * 128];   // 2 x 8 KB fp8 swizzled tile image
  __shared__ uint4 Vs4[2][128];                  // 2 x 2 KB f16 V pair-frags
  int t = threadIdx.x;
  int lane = t & 63;
  int wave = t >> 6;    // 0..3
  int q = lane >> 4;    // 0..3
  int r = lane & 15;    // 0..15
  int i0 = blockIdx.x * BI + wave * 64;
  int jbase = blockIdx.y * JSEG;

  // stationary B-frags: 4 i-sets, 32 fp8 bytes/lane (chunks 2q, 2q+1 of row)
  i32x8 bfr[4];
#pragma unroll
  for (int s = 0; s < 4; ++s) {
    int row = i0 + s * 16 + r;
    union { uint4 h[2]; i32x8 v; } bb;
    bb.h[0] = *(const uint4*)(F8 + f8idx(row, 2 * q));
    bb.h[1] = *(const uint4*)(F8 + f8idx(row, 2 * q + 1));
    bfr[s] = bb.v;
  }

  f32x4 acc[4];
#pragma unroll
  for (int s = 0; s < 4; ++s) acc[s] = (f32x4){0.f, 0.f, 0.f, 0.f};
  const f32x4 kZero = {0.f, 0.f, 0.f, 0.f};

  // ---- staging helper ----
  // j0 is a multiple of 64; the 64-row half of the 128-row F8 macro-tile is
  // contiguous: base = (j0>>7)*16384 + (j0&64)*128. Swizzle is row&7-local and
  // 64-row tiles preserve row&7, so the compute-side chunk XOR is unchanged.
  auto stage = [&](int buf, int j0) {
    const uint4* srcF = (const uint4*)(F8 + (((size_t)(j0 >> 7)) << 14)
                                          + (((size_t)(j0 & 64)) << 7));
#pragma unroll
    for (int k = 0; k < 2; ++k) {
      int off = (k << 8) + t;   // 16B-chunk idx 0..511, lane-consecutive per wave
      __builtin_amdgcn_global_load_lds(
          (const __attribute__((address_space(1))) uint4*)(srcF + off),
          (__attribute__((address_space(3))) uint4*)((uint4*)Fs[buf] + off), 16, 0, 0);
    }
    if (t < 128) {   // 2 pair-groups x 64 chunks
      const uint4* srcV = (const uint4*)VF + ((size_t)(j0 >> 5) << 6);
      __builtin_amdgcn_global_load_lds(
          (const __attribute__((address_space(1))) uint4*)(srcV + t),
          (__attribute__((address_space(3))) uint4*)(Vs4[buf] + t), 16, 0, 0);
    }
  };

  auto compute = [&](int buf) {
    const u8* fsb = Fs[buf];
    const uint4* vsb = Vs4[buf];
#pragma unroll
    for (int jp = 0; jp < 2; ++jp) {   // pairs of 16-row j-chunks (64 rows total)
      union { uint4 h[2]; i32x8 v; } afe, afo;
      const u8* re = fsb + (jp * 32 + r) * 128;       // even chunk row
      const u8* ro = re + 16 * 128;                   // odd chunk row
      int c0 = (((2 * q) ^ (r & 7)) & 7) << 4;
      int c1 = (((2 * q + 1) ^ (r & 7)) & 7) << 4;
      afe.h[0] = *(const uint4*)(re + c0);
      afe.h[1] = *(const uint4*)(re + c1);
      afo.h[0] = *(const uint4*)(ro + c0);
      afo.h[1] = *(const uint4*)(ro + c1);
      union { uint4 qd; f16x8 v; } bv;
      bv.qd = vsb[jp * 64 + lane];

      // prologue: QK pair for s=0
      __builtin_amdgcn_s_setprio(1);
      f32x4 ce = __builtin_amdgcn_mfma_scale_f32_16x16x128_f8f6f4(
          afe.v, bfr[0], kZero, 0, 0, 0, 0x7F7F7F7Fu, 0, 0x7F7F7F7Fu);
      f32x4 co = __builtin_amdgcn_mfma_scale_f32_16x16x128_f8f6f4(
          afo.v, bfr[0], kZero, 0, 0, 0, 0x7F7F7F7Fu, 0, 0x7F7F7F7Fu);
      __builtin_amdgcn_s_setprio(0);
#pragma unroll
      for (int s = 0; s < 4; ++s) {
        f32x4 cen, con;
        if (s < 3) {   // issue next QK pair BEFORE consuming this one
          __builtin_amdgcn_s_setprio(1);
          cen = __builtin_amdgcn_mfma_scale_f32_16x16x128_f8f6f4(
              afe.v, bfr[s + 1], kZero, 0, 0, 0, 0x7F7F7F7Fu, 0, 0x7F7F7F7Fu);
          con = __builtin_amdgcn_mfma_scale_f32_16x16x128_f8f6f4(
              afo.v, bfr[s + 1], kZero, 0, 0, 0, 0x7F7F7F7Fu, 0, 0x7F7F7F7Fu);
          __builtin_amdgcn_s_setprio(0);
        }
        union { u32 u[4]; f16x8 v; } pf;
        pf.u[0] = packexp2f16(ce[0], ce[1]);
        pf.u[1] = packexp2f16(ce[2], ce[3]);
        pf.u[2] = packexp2f16(co[0], co[1]);
        pf.u[3] = packexp2f16(co[2], co[3]);
        __builtin_amdgcn_s_setprio(1);
        acc[s] = __builtin_amdgcn_mfma_f32_16x16x32_f16(pf.v, bv.v, acc[s], 0, 0, 0);
        __builtin_amdgcn_s_setprio(0);
        if (s < 3) { ce = cen; co = con; }
      }
    }
  };

  // ---- double-buffered pipeline over the 16 tiles of this j-segment ----
  stage(0, jbase);
  __syncthreads();
#pragma unroll
  for (int jt = 0; jt < NTILE - 1; ++jt) {
    stage((jt + 1) & 1, jbase + (jt + 1) * BJ);  // prefetch overlaps compute
    compute(jt & 1);
    __syncthreads();  // drain waits on loads that ran under compute
  }
  compute((NTILE - 1) & 1);

  // acc[s] lane(q,r) reg rg = partial[row = i0+s*16+q*4+rg][col = r]
  // V cols 11..15 are structurally zero -> the r==11 lane stores exact zeros,
  // keeping the slab's pad column clean for kfinal's float4 accumulation.
  if (r < 12) {
    float* base = Ppart + ((size_t)blockIdx.y * NROWS + (size_t)i0) * VW;
#pragma unroll
    for (int s = 0; s < 4; ++s) {
      float* op = base + (s * 16 + q * 4) * VW + r;
      op[0 * VW] = acc[s][0];
      op[1 * VW] = acc[s][1];
      op[2 * VW] = acc[s][2];
      op[3 * VW] = acc[s][3];
    }
  }
}

// ---------------- finalize: slab reduce + class-count reduce + divides ----------------
__global__ void kfinal(float* __restrict__ out, const float* __restrict__ Ppart,
                       const float* __restrict__ clsPart) {
  __shared__ float clsS[16];
  int t = threadIdx.x;
  if (t < 64) {
    const float4* cp = (const float4*)clsPart;  // 64 rows x 4 float4
    float4 c0 = cp[t * 4], c1 = cp[t * 4 + 1], c2 = cp[t * 4 + 2], c3 = cp[t * 4 + 3];
#pragma unroll
    for (int off = 32; off >= 1; off >>= 1) {
      c0.x += __shfl_xor(c0.x, off); c0.y += __shfl_xor(c0.y, off);
      c0.z += __shfl_xor(c0.z, off); c0.w += __shfl_xor(c0.w, off);
      c1.x += __shfl_xor(c1.x, off); c1.y += __shfl_xor(c1.y, off);
      c1.z += __shfl_xor(c1.z, off); c1.w += __shfl_xor(c1.w, off);
      c2.x += __shfl_xor(c2.x, off); c2.y += __shfl_xor(c2.y, off);
    }
    if (t == 0) {
      *(float4*)&clsS[0] = c0;
      *(float4*)&clsS[4] = c1;
      clsS[8] = c2.x; clsS[9] = c2.y;
      clsS[10] = 0.f; clsS[11] = 0.f; clsS[12] = 0.f;
      clsS[13] = 0.f; clsS[14] = 0.f; clsS[15] = 0.f;
    }
  }
  __syncthreads();
  float d[NC]; float tot = 0.0f;
#pragma unroll
  for (int c = 0; c < NC; ++c) { d[c] = clsS[c]; tot += d[c]; }

  int row = blockIdx.x * 256 + t;  // 64 blocks x 256
  float4 a0 = {0.f, 0.f, 0.f, 0.f}, a1 = a0, a2 = a0;
#pragma unroll
  for (int s = 0; s < SEG; ++s) {
    const float4* pr = (const float4*)(Ppart + ((size_t)s * NROWS + (size_t)row) * VW);
    float4 x0 = pr[0], x1 = pr[1], x2 = pr[2];
    a0.x += x0.x; a0.y += x0.y; a0.z += x0.z; a0.w += x0.w;
    a1.x += x1.x; a1.y += x1.y; a1.z += x1.z; a1.w += x1.w;
    a2.x += x2.x; a2.y += x2.y; a2.z += x2.z;
  }
  float num[NC] = {a0.x, a0.y, a0.z, a0.w, a1.x, a1.y, a1.z, a1.w, a2.x, a2.y};
  float rs = 1.0f / a2.z;   // col 10 = attention denominator
  float* op = out + (size_t)row * NC;
#pragma unroll
  for (int c = 0; c < NC; ++c) {
    float den = (d[c] == 0.0f) ? tot : d[c];
    op[c] = num[c] * rs / den;
  }
}

extern "C" void kernel_launch(void* const* d_in, const int* in_sizes, int n_in,
                              void* d_out, int out_size, void* d_ws, size_t ws_size,
                              hipStream_t stream) {
  const float* anchor   = (const float*)d_in[0];  // 6144x128
  const float* positive = (const float*)d_in[1];  // 6144x128
  const float* lbfeat   = (const float*)d_in[2];  // 4096x128
  const float* onehot   = (const float*)d_in[3];  // 4096x10
  const float* l1       = (const float*)d_in[4];  // 6144x10
  const float* l2       = (const float*)d_in[5];  // 6144x10
  float* out = (float*)d_out;                     // 16384x10

  char* ws = (char*)d_ws;
  u8*     F8      = (u8*)ws;                                 // 2 MiB fp8 swizzled image
  f16_t*  VF      = (f16_t*)(ws + 2097152);                  // 512 KiB f16 pair-frags
  float*  Ppart   = (float*)(ws + 2097152 + 524288);         // SEG*NROWS*VW*4 = 12 MiB
  float*  clsPart = (float*)(ws + 2097152 + 524288 + (size_t)SEG * NROWS * VW * 4);  // 4 KiB

  kprep2<<<1088, 256, 0, stream>>>(lbfeat, anchor, positive, onehot, l1, l2,
                                   F8, VF, clsPart);
  kattn<<<dim3(NROWS / BI, SEG), 256, 0, stream>>>(F8, VF, Ppart);
  kfinal<<<NROWS / 256, 256, 0, stream>>>(out, Ppart, clsPart);
}

// Round 4
// 112.680 us; speedup vs baseline: 1.0203x; 1.0203x over previous
//
#include <hip/hip_runtime.h>
#include <hip/hip_bf16.h>

#define NLB 4096
#define NULB 6144
#define NROWS 16384   // 4096 + 2*6144
#define DD 128
#define NC 10
#define VW 12                // partial-slab row width: 10 numerators + denom + zero pad
#define SEG 16               // j-segments: grid (64,16)=1024 = 4 blocks/CU, no tail
#define JSEG (NROWS / SEG)   // 1024
#define NTILE (JSEG / 64)    // 16 tiles per segment
#define BI 256               // i-rows per block (4 waves x 64)
#define BJ 64                // j-rows per LDS tile: LDS 20480 B
#define NVB 256              // V-build blocks (R16: was 64) -> 64 rows each
#define SQRTC 1.6986437f     // sqrt(2*log2(e))

typedef __bf16 bf16_t;
typedef _Float16 f16_t;
typedef f16_t f16x8 __attribute__((ext_vector_type(8)));
typedef float f32x4 __attribute__((ext_vector_type(4)));
typedef short i16x2 __attribute__((ext_vector_type(2)));
typedef int i32x8 __attribute__((ext_vector_type(8)));
typedef unsigned int u32;
typedef unsigned char u8;

// fp8 F global layout = swizzled LDS image, 128-row tiles of 128-byte rows:
//   byte address(row, 16B-chunk c0..7) =
//     (row>>7)*16384 + (row&127)*128 + ((c ^ (row&7)) << 4)
__device__ __forceinline__ size_t f8idx(int row, int c) {
  return ((size_t)(row >> 7) << 14) + (size_t)((row & 127) << 7)
       + (size_t)(((c ^ (row & 7)) & 7) << 4);
}

// pack two f16(2^(c/256)) into one dword (fma + pknorm per pair).
// f16 bits of 2^x ~= round(1024x + 15315.35); x = c/256 -> 4*c.
// pknorm: i16 = round(y*32767) -> y = c*(4/32767) + 15315.35/32767.
// staircase rel err ~0.2%, mean-zero, common-mode num/denom.
__device__ __forceinline__ u32 packexp2f16(float c0, float c1) {
#if __has_builtin(__builtin_amdgcn_cvt_pknorm_i16)
  float y0 = fmaf(c0, 1.2207465e-4f, 0.46740490f);
  float y1 = fmaf(c1, 1.2207465e-4f, 0.46740490f);
  union { i16x2 p; u32 u; } cv;
  cv.p = __builtin_amdgcn_cvt_pknorm_i16(y0, y1);
  return cv.u;
#else
  u32 b0 = (u32)(int)fmaf(c0, 4.0f, 15315.354f);
  u32 b1 = (u32)(int)fmaf(c1, 4.0f, 15315.354f);
  return __builtin_amdgcn_perm(b1, b0, 0x05040100u);
#endif
}

// ================= fused prep =================
// R16: the V-build tail was 64 blocks (serial on 64 CUs after the 1024 F8
// blocks drain) -> spread to 256 blocks x 64 rows so the expf chains use 4x
// the CUs. Same math; clsPart grows to 256 partial rows.
// blocks 0..1023    : L2-normalize 16 rows each of [lb;anchor;pos], scale by
//                     16*SQRTC, fp8 e4m3 into swizzled F image.
// blocks 1024..1279 : build f16 V fragments (32-row pair-groups) + per-block
//                     class-count partials, 64 rows per block.
// VF layout: pair-group G (32 j-rows), lane l=(q=l>>4, n=l&15), 16B chunk:
//   f16 V[G*32 + q*4 + d][n] d=0..3, then f16 V[G*32+16 + q*4 + d][n] d=0..3
//   == f16 PV B-frag with k=q*8+{0..3} = even 16-chunk, {4..7} = odd.
__global__ void kprep2(const float* __restrict__ lb, const float* __restrict__ an,
                       const float* __restrict__ po, const float* __restrict__ onehot,
                       const float* __restrict__ l1, const float* __restrict__ l2,
                       u8* __restrict__ F8, f16_t* __restrict__ VF,
                       float* __restrict__ clsPart) {
  __shared__ float Vtmp[64 * 16];
  __shared__ float lcnt[NC];
  int b = blockIdx.x;
  int t = threadIdx.x;

  if (b < 1024) {
    int row = b * 16 + (t >> 4);
    int c = t & 15;           // lane's 8 floats = k bytes c*8 .. c*8+7
    const float* src;
    if (row < NLB) src = lb + (size_t)row * DD;
    else if (row < NLB + NULB) src = an + (size_t)(row - NLB) * DD;
    else src = po + (size_t)(row - NLB - NULB) * DD;
    float4 v0 = ((const float4*)src)[c * 2];
    float4 v1 = ((const float4*)src)[c * 2 + 1];
    float ss = v0.x*v0.x + v0.y*v0.y + v0.z*v0.z + v0.w*v0.w
             + v1.x*v1.x + v1.y*v1.y + v1.z*v1.z + v1.w*v1.w;
#pragma unroll
    for (int off = 8; off >= 1; off >>= 1) ss += __shfl_xor(ss, off);
    float inv = (16.0f * SQRTC) / fmaxf(sqrtf(ss), 1e-12f);
    u32 d0 = (u32)__builtin_amdgcn_cvt_pk_fp8_f32(v0.x*inv, v0.y*inv, 0, false);
    d0 = (u32)__builtin_amdgcn_cvt_pk_fp8_f32(v0.z*inv, v0.w*inv, d0, true);
    u32 d1 = (u32)__builtin_amdgcn_cvt_pk_fp8_f32(v1.x*inv, v1.y*inv, 0, false);
    d1 = (u32)__builtin_amdgcn_cvt_pk_fp8_f32(v1.z*inv, v1.w*inv, d1, true);
    uint2 dd = {d0, d1};
    *(uint2*)(F8 + f8idx(row, c >> 1) + ((c & 1) << 3)) = dd;
    return;
  }

  // ---- V build: 64 rows/block, 256 blocks over all 16384 output rows ----
  int vb = b - 1024;          // 0..255
  if (t < NC) lcnt[t] = 0.0f;
  __syncthreads();
  if (t < 64) {
    int gid = vb * 64 + t;
    float p[16];
    p[10] = 1.0f; p[11] = 0.f; p[12] = 0.f; p[13] = 0.f; p[14] = 0.f; p[15] = 0.f;
    if (gid < NLB) {
      int idx = 0;
#pragma unroll
      for (int c = 0; c < NC; ++c) {
        p[c] = onehot[(size_t)gid * NC + c];
        if (p[c] == 1.0f) idx = c;
      }
      atomicAdd(&lcnt[idx], 1.0f);
    } else {
      int r = (gid < NLB + NULB) ? (gid - NLB) : (gid - NLB - NULB);
      bool count = (gid < NLB + NULB);
      float a[NC], bb[NC];
#pragma unroll
      for (int c = 0; c < NC; ++c) { a[c] = l1[(size_t)r * NC + c]; bb[c] = l2[(size_t)r * NC + c]; }
      float m1 = a[0], m2 = bb[0];
#pragma unroll
      for (int c = 1; c < NC; ++c) { m1 = fmaxf(m1, a[c]); m2 = fmaxf(m2, bb[c]); }
      float s1 = 0.0f, s2 = 0.0f;
#pragma unroll
      for (int c = 0; c < NC; ++c) {
        s1 += expf(2.0f * (a[c] - m1));
        s2 += expf(2.0f * (bb[c] - m2));
      }
      bool take1 = (s1 <= s2);  // max(prob1)=1/s1 >= 1/s2=max(prob2)
      float g[NC];
#pragma unroll
      for (int c = 0; c < NC; ++c) g[c] = take1 ? a[c] : bb[c];
      float mg = g[0];
#pragma unroll
      for (int c = 1; c < NC; ++c) mg = fmaxf(mg, g[c]);
      float e[NC]; float sg = 0.0f;
#pragma unroll
      for (int c = 0; c < NC; ++c) { e[c] = expf(g[c] - mg); sg += e[c]; }
      float msk[NC];
#pragma unroll
      for (int c = 0; c < NC; ++c) msk[c] = ((e[c] / sg) >= 0.95f) ? g[c] : 0.0f;
      float mx = msk[0]; int mi = 0;
#pragma unroll
      for (int c = 1; c < NC; ++c) if (msk[c] > mx) { mx = msk[c]; mi = c; }
      if (count && mx != 0.0f) atomicAdd(&lcnt[mi], 2.0f);
      float mm = 2.0f * msk[0];
#pragma unroll
      for (int c = 1; c < NC; ++c) mm = fmaxf(mm, 2.0f * msk[c]);
      float q[NC]; float sp = 0.0f;
#pragma unroll
      for (int c = 0; c < NC; ++c) { q[c] = expf(2.0f * msk[c] - mm); sp += q[c]; }
#pragma unroll
      for (int c = 0; c < NC; ++c) p[c] = q[c] / sp;
    }
#pragma unroll
    for (int c = 0; c < 16; ++c) Vtmp[t * 16 + c] = p[c];
  }
  __syncthreads();
  if (t < 16) clsPart[(size_t)vb * 16 + t] = (t < NC) ? lcnt[t] : 0.0f;
  // scatter to VF f16 pair-frag layout: 2 pair-groups x 64 chunks per block
  if (t < 128) {
    int gbase = vb * 2;          // global pair-group base (0..511)
    int G = t >> 6;              // local pair-group 0..1
    int l = t & 63;
    int q = l >> 4;
    int n = l & 15;
    union { f16_t h[8]; uint4 uu; } pk;
#pragma unroll
    for (int d = 0; d < 4; ++d) {
      pk.h[d]     = (f16_t)Vtmp[(G * 32      + q * 4 + d) * 16 + n];
      pk.h[4 + d] = (f16_t)Vtmp[(G * 32 + 16 + q * 4 + d) * 16 + n];
    }
    *(uint4*)(VF + ((size_t)(gbase + G) * 64 + l) * 8) = pk.uu;
  }
}

// ================= attention partials =================
// Unchanged from R15 (depth-2 s-pipeline + setprio: measured neutral, kept).
// History: R13 showed device-scope atomic epilogue becomes a ~500 MB RMW
// storm when co-resident -> R14 streams private per-(i-block, j-seg) slabs,
// reduced in kfinal. BJ=64/SEG=16: LDS 20480 B, grid (64,16)=1024 = 4
// blocks/CU, zero tail. QK: one mfma_scale_f32_16x16x128_f8f6f4 per 16x16
// tile. PV: even/odd 16-row chunks paired in one mfma_f32_16x16x32_f16.
// Double-buffered: stage tile jt+1 before computing tile jt so the
// vmcnt(0)-before-barrier drain waits on loads that overlapped compute.
__launch_bounds__(256, 4)
__global__ void kattn(const u8* __restrict__ F8, const f16_t* __restrict__ VF,
                      float* __restrict__ Ppart) {
  __shared__ __align__(16) u8 Fs[2][BJ * 128];   // 2 x 8 KB fp8 swizzled tile image
  __shared__ uint4 Vs4[2][128];                  // 2 x 2 KB f16 V pair-frags
  int t = threadIdx.x;
  int lane = t & 63;
  int wave = t >> 6;    // 0..3
  int q = lane >> 4;    // 0..3
  int r = lane & 15;    // 0..15
  int i0 = blockIdx.x * BI + wave * 64;
  int jbase = blockIdx.y * JSEG;

  // stationary B-frags: 4 i-sets, 32 fp8 bytes/lane (chunks 2q, 2q+1 of row)
  i32x8 bfr[4];
#pragma unroll
  for (int s = 0; s < 4; ++s) {
    int row = i0 + s * 16 + r;
    union { uint4 h[2]; i32x8 v; } bb;
    bb.h[0] = *(const uint4*)(F8 + f8idx(row, 2 * q));
    bb.h[1] = *(const uint4*)(F8 + f8idx(row, 2 * q + 1));
    bfr[s] = bb.v;
  }

  f32x4 acc[4];
#pragma unroll
  for (int s = 0; s < 4; ++s) acc[s] = (f32x4){0.f, 0.f, 0.f, 0.f};
  const f32x4 kZero = {0.f, 0.f, 0.f, 0.f};

  // ---- staging helper ----
  // j0 is a multiple of 64; the 64-row half of the 128-row F8 macro-tile is
  // contiguous: base = (j0>>7)*16384 + (j0&64)*128. Swizzle is row&7-local and
  // 64-row tiles preserve row&7, so the compute-side chunk XOR is unchanged.
  auto stage = [&](int buf, int j0) {
    const uint4* srcF = (const uint4*)(F8 + (((size_t)(j0 >> 7)) << 14)
                                          + (((size_t)(j0 & 64)) << 7));
#pragma unroll
    for (int k = 0; k < 2; ++k) {
      int off = (k << 8) + t;   // 16B-chunk idx 0..511, lane-consecutive per wave
      __builtin_amdgcn_global_load_lds(
          (const __attribute__((address_space(1))) uint4*)(srcF + off),
          (__attribute__((address_space(3))) uint4*)((uint4*)Fs[buf] + off), 16, 0, 0);
    }
    if (t < 128) {   // 2 pair-groups x 64 chunks
      const uint4* srcV = (const uint4*)VF + ((size_t)(j0 >> 5) << 6);
      __builtin_amdgcn_global_load_lds(
          (const __attribute__((address_space(1))) uint4*)(srcV + t),
          (__attribute__((address_space(3))) uint4*)(Vs4[buf] + t), 16, 0, 0);
    }
  };

  auto compute = [&](int buf) {
    const u8* fsb = Fs[buf];
    const uint4* vsb = Vs4[buf];
#pragma unroll
    for (int jp = 0; jp < 2; ++jp) {   // pairs of 16-row j-chunks (64 rows total)
      union { uint4 h[2]; i32x8 v; } afe, afo;
      const u8* re = fsb + (jp * 32 + r) * 128;       // even chunk row
      const u8* ro = re + 16 * 128;                   // odd chunk row
      int c0 = (((2 * q) ^ (r & 7)) & 7) << 4;
      int c1 = (((2 * q + 1) ^ (r & 7)) & 7) << 4;
      afe.h[0] = *(const uint4*)(re + c0);
      afe.h[1] = *(const uint4*)(re + c1);
      afo.h[0] = *(const uint4*)(ro + c0);
      afo.h[1] = *(const uint4*)(ro + c1);
      union { uint4 qd; f16x8 v; } bv;
      bv.qd = vsb[jp * 64 + lane];

      // prologue: QK pair for s=0
      __builtin_amdgcn_s_setprio(1);
      f32x4 ce = __builtin_amdgcn_mfma_scale_f32_16x16x128_f8f6f4(
          afe.v, bfr[0], kZero, 0, 0, 0, 0x7F7F7F7Fu, 0, 0x7F7F7F7Fu);
      f32x4 co = __builtin_amdgcn_mfma_scale_f32_16x16x128_f8f6f4(
          afo.v, bfr[0], kZero, 0, 0, 0, 0x7F7F7F7Fu, 0, 0x7F7F7F7Fu);
      __builtin_amdgcn_s_setprio(0);
#pragma unroll
      for (int s = 0; s < 4; ++s) {
        f32x4 cen, con;
        if (s < 3) {   // issue next QK pair BEFORE consuming this one
          __builtin_amdgcn_s_setprio(1);
          cen = __builtin_amdgcn_mfma_scale_f32_16x16x128_f8f6f4(
              afe.v, bfr[s + 1], kZero, 0, 0, 0, 0x7F7F7F7Fu, 0, 0x7F7F7F7Fu);
          con = __builtin_amdgcn_mfma_scale_f32_16x16x128_f8f6f4(
              afo.v, bfr[s + 1], kZero, 0, 0, 0, 0x7F7F7F7Fu, 0, 0x7F7F7F7Fu);
          __builtin_amdgcn_s_setprio(0);
        }
        union { u32 u[4]; f16x8 v; } pf;
        pf.u[0] = packexp2f16(ce[0], ce[1]);
        pf.u[1] = packexp2f16(ce[2], ce[3]);
        pf.u[2] = packexp2f16(co[0], co[1]);
        pf.u[3] = packexp2f16(co[2], co[3]);
        __builtin_amdgcn_s_setprio(1);
        acc[s] = __builtin_amdgcn_mfma_f32_16x16x32_f16(pf.v, bv.v, acc[s], 0, 0, 0);
        __builtin_amdgcn_s_setprio(0);
        if (s < 3) { ce = cen; co = con; }
      }
    }
  };

  // ---- double-buffered pipeline over the 16 tiles of this j-segment ----
  stage(0, jbase);
  __syncthreads();
#pragma unroll
  for (int jt = 0; jt < NTILE - 1; ++jt) {
    stage((jt + 1) & 1, jbase + (jt + 1) * BJ);  // prefetch overlaps compute
    compute(jt & 1);
    __syncthreads();  // drain waits on loads that ran under compute
  }
  compute((NTILE - 1) & 1);

  // acc[s] lane(q,r) reg rg = partial[row = i0+s*16+q*4+rg][col = r]
  // V cols 11..15 are structurally zero -> the r==11 lane stores exact zeros,
  // keeping the slab's pad column clean for kfinal's float4 accumulation.
  if (r < 12) {
    float* base = Ppart + ((size_t)blockIdx.y * NROWS + (size_t)i0) * VW;
#pragma unroll
    for (int s = 0; s < 4; ++s) {
      float* op = base + (s * 16 + q * 4) * VW + r;
      op[0 * VW] = acc[s][0];
      op[1 * VW] = acc[s][1];
      op[2 * VW] = acc[s][2];
      op[3 * VW] = acc[s][3];
    }
  }
}

// ---------------- finalize: slab reduce + class-count reduce + divides ----------------
// R16: spread 64x256 -> 256 blocks x 64 threads (1 row/thread, full-chip
// read of the 12.6 MB slab instead of 64 CUs). clsPart is now 256 partial
// rows: each lane sums 4 rows, then a 64-lane shuffle reduce.
__global__ void kfinal(float* __restrict__ out, const float* __restrict__ Ppart,
                       const float* __restrict__ clsPart) {
  __shared__ float clsS[16];
  int t = threadIdx.x;   // 0..63, one wave
  const float4* cp = (const float4*)clsPart;  // 256 rows x 4 float4
  float4 c0 = {0.f, 0.f, 0.f, 0.f}, c1 = c0;
  float c2x = 0.f, c2y = 0.f;
#pragma unroll
  for (int k = 0; k < 4; ++k) {
    int rr = t + 64 * k;
    float4 x0 = cp[rr * 4], x1 = cp[rr * 4 + 1], x2 = cp[rr * 4 + 2];
    c0.x += x0.x; c0.y += x0.y; c0.z += x0.z; c0.w += x0.w;
    c1.x += x1.x; c1.y += x1.y; c1.z += x1.z; c1.w += x1.w;
    c2x += x2.x; c2y += x2.y;
  }
#pragma unroll
  for (int off = 32; off >= 1; off >>= 1) {
    c0.x += __shfl_xor(c0.x, off); c0.y += __shfl_xor(c0.y, off);
    c0.z += __shfl_xor(c0.z, off); c0.w += __shfl_xor(c0.w, off);
    c1.x += __shfl_xor(c1.x, off); c1.y += __shfl_xor(c1.y, off);
    c1.z += __shfl_xor(c1.z, off); c1.w += __shfl_xor(c1.w, off);
    c2x += __shfl_xor(c2x, off); c2y += __shfl_xor(c2y, off);
  }
  if (t == 0) {
    *(float4*)&clsS[0] = c0;
    *(float4*)&clsS[4] = c1;
    clsS[8] = c2x; clsS[9] = c2y;
    clsS[10] = 0.f; clsS[11] = 0.f; clsS[12] = 0.f;
    clsS[13] = 0.f; clsS[14] = 0.f; clsS[15] = 0.f;
  }
  __syncthreads();
  float d[NC]; float tot = 0.0f;
#pragma unroll
  for (int c = 0; c < NC; ++c) { d[c] = clsS[c]; tot += d[c]; }

  int row = blockIdx.x * 64 + t;  // 256 blocks x 64
  float4 a0 = {0.f, 0.f, 0.f, 0.f}, a1 = a0, a2 = a0;
#pragma unroll
  for (int s = 0; s < SEG; ++s) {
    const float4* pr = (const float4*)(Ppart + ((size_t)s * NROWS + (size_t)row) * VW);
    float4 x0 = pr[0], x1 = pr[1], x2 = pr[2];
    a0.x += x0.x; a0.y += x0.y; a0.z += x0.z; a0.w += x0.w;
    a1.x += x1.x; a1.y += x1.y; a1.z += x1.z; a1.w += x1.w;
    a2.x += x2.x; a2.y += x2.y; a2.z += x2.z;
  }
  float num[NC] = {a0.x, a0.y, a0.z, a0.w, a1.x, a1.y, a1.z, a1.w, a2.x, a2.y};
  float rs = 1.0f / a2.z;   // col 10 = attention denominator
  float* op = out + (size_t)row * NC;
#pragma unroll
  for (int c = 0; c < NC; ++c) {
    float den = (d[c] == 0.0f) ? tot : d[c];
    op[c] = num[c] * rs / den;
  }
}

extern "C" void kernel_launch(void* const* d_in, const int* in_sizes, int n_in,
                              void* d_out, int out_size, void* d_ws, size_t ws_size,
                              hipStream_t stream) {
  const float* anchor   = (const float*)d_in[0];  // 6144x128
  const float* positive = (const float*)d_in[1];  // 6144x128
  const float* lbfeat   = (const float*)d_in[2];  // 4096x128
  const float* onehot   = (const float*)d_in[3];  // 4096x10
  const float* l1       = (const float*)d_in[4];  // 6144x10
  const float* l2       = (const float*)d_in[5];  // 6144x10
  float* out = (float*)d_out;                     // 16384x10

  char* ws = (char*)d_ws;
  u8*     F8      = (u8*)ws;                                 // 2 MiB fp8 swizzled image
  f16_t*  VF      = (f16_t*)(ws + 2097152);                  // 512 KiB f16 pair-frags
  float*  Ppart   = (float*)(ws + 2097152 + 524288);         // SEG*NROWS*VW*4 = 12 MiB
  float*  clsPart = (float*)(ws + 2097152 + 524288 + (size_t)SEG * NROWS * VW * 4);  // 16 KiB

  kprep2<<<1024 + NVB, 256, 0, stream>>>(lbfeat, anchor, positive, onehot, l1, l2,
                                         F8, VF, clsPart);
  kattn<<<dim3(NROWS / BI, SEG), 256, 0, stream>>>(F8, VF, Ppart);
  kfinal<<<NVB, 64, 0, stream>>>(out, Ppart, clsPart);
}

// Round 5
// 111.100 us; speedup vs baseline: 1.0348x; 1.0142x over previous
//
#include <hip/hip_runtime.h>
#include <hip/hip_bf16.h>

#define NLB 4096
#define NULB 6144
#define NROWS 16384   // 4096 + 2*6144
#define DD 128
#define NC 10
#define VW 12                // partial-slab row width: 10 numerators + denom + zero pad
#define SEG 16               // j-segments: grid (64,16)=1024 = 4 blocks/CU, no tail
#define JSEG (NROWS / SEG)   // 1024
#define NTILE (JSEG / 64)    // 16 tiles per segment
#define BI 256               // i-rows per block (4 waves x 64)
#define BJ 64                // j-rows per LDS tile
#define NVB 256              // V-build blocks -> 64 rows each
#define SQRTC 1.6986437f     // sqrt(2*log2(e))

typedef __bf16 bf16_t;
typedef _Float16 f16_t;
typedef f16_t f16x8 __attribute__((ext_vector_type(8)));
typedef float f32x4 __attribute__((ext_vector_type(4)));
typedef short i16x2 __attribute__((ext_vector_type(2)));
typedef int i32x8 __attribute__((ext_vector_type(8)));
typedef unsigned int u32;
typedef unsigned char u8;

// fp8 F global layout = swizzled LDS image, 128-row tiles of 128-byte rows:
//   byte address(row, 16B-chunk c0..7) =
//     (row>>7)*16384 + (row&127)*128 + ((c ^ (row&7)) << 4)
__device__ __forceinline__ size_t f8idx(int row, int c) {
  return ((size_t)(row >> 7) << 14) + (size_t)((row & 127) << 7)
       + (size_t)(((c ^ (row & 7)) & 7) << 4);
}

// pack two f16(2^(c/256)) into one dword (fma + pknorm per pair).
// f16 bits of 2^x ~= round(1024x + 15315.35); x = c/256 -> 4*c.
// pknorm: i16 = round(y*32767) -> y = c*(4/32767) + 15315.35/32767.
// staircase rel err ~0.2%, mean-zero, common-mode num/denom.
__device__ __forceinline__ u32 packexp2f16(float c0, float c1) {
#if __has_builtin(__builtin_amdgcn_cvt_pknorm_i16)
  float y0 = fmaf(c0, 1.2207465e-4f, 0.46740490f);
  float y1 = fmaf(c1, 1.2207465e-4f, 0.46740490f);
  union { i16x2 p; u32 u; } cv;
  cv.p = __builtin_amdgcn_cvt_pknorm_i16(y0, y1);
  return cv.u;
#else
  u32 b0 = (u32)(int)fmaf(c0, 4.0f, 15315.354f);
  u32 b1 = (u32)(int)fmaf(c1, 4.0f, 15315.354f);
  return __builtin_amdgcn_perm(b1, b0, 0x05040100u);
#endif
}

// ================= fused prep =================
// blocks 0..1023    : L2-normalize 16 rows each of [lb;anchor;pos], scale by
//                     16*SQRTC, fp8 e4m3 into swizzled F image.
// blocks 1024..1279 : build f16 V fragments (32-row pair-groups) + per-block
//                     class-count partials, 64 rows per block (R16 spread).
// VF layout: pair-group G (32 j-rows), lane l=(q=l>>4, n=l&15), 16B chunk:
//   f16 V[G*32 + q*4 + d][n] d=0..3, then f16 V[G*32+16 + q*4 + d][n] d=0..3
//   == f16 PV B-frag with k=q*8+{0..3} = even 16-chunk, {4..7} = odd.
__global__ void kprep2(const float* __restrict__ lb, const float* __restrict__ an,
                       const float* __restrict__ po, const float* __restrict__ onehot,
                       const float* __restrict__ l1, const float* __restrict__ l2,
                       u8* __restrict__ F8, f16_t* __restrict__ VF,
                       float* __restrict__ clsPart) {
  __shared__ float Vtmp[64 * 16];
  __shared__ float lcnt[NC];
  int b = blockIdx.x;
  int t = threadIdx.x;

  if (b < 1024) {
    int row = b * 16 + (t >> 4);
    int c = t & 15;           // lane's 8 floats = k bytes c*8 .. c*8+7
    const float* src;
    if (row < NLB) src = lb + (size_t)row * DD;
    else if (row < NLB + NULB) src = an + (size_t)(row - NLB) * DD;
    else src = po + (size_t)(row - NLB - NULB) * DD;
    float4 v0 = ((const float4*)src)[c * 2];
    float4 v1 = ((const float4*)src)[c * 2 + 1];
    float ss = v0.x*v0.x + v0.y*v0.y + v0.z*v0.z + v0.w*v0.w
             + v1.x*v1.x + v1.y*v1.y + v1.z*v1.z + v1.w*v1.w;
#pragma unroll
    for (int off = 8; off >= 1; off >>= 1) ss += __shfl_xor(ss, off);
    float inv = (16.0f * SQRTC) / fmaxf(sqrtf(ss), 1e-12f);
    u32 d0 = (u32)__builtin_amdgcn_cvt_pk_fp8_f32(v0.x*inv, v0.y*inv, 0, false);
    d0 = (u32)__builtin_amdgcn_cvt_pk_fp8_f32(v0.z*inv, v0.w*inv, d0, true);
    u32 d1 = (u32)__builtin_amdgcn_cvt_pk_fp8_f32(v1.x*inv, v1.y*inv, 0, false);
    d1 = (u32)__builtin_amdgcn_cvt_pk_fp8_f32(v1.z*inv, v1.w*inv, d1, true);
    uint2 dd = {d0, d1};
    *(uint2*)(F8 + f8idx(row, c >> 1) + ((c & 1) << 3)) = dd;
    return;
  }

  // ---- V build: 64 rows/block, 256 blocks over all 16384 output rows ----
  int vb = b - 1024;          // 0..255
  if (t < NC) lcnt[t] = 0.0f;
  __syncthreads();
  if (t < 64) {
    int gid = vb * 64 + t;
    float p[16];
    p[10] = 1.0f; p[11] = 0.f; p[12] = 0.f; p[13] = 0.f; p[14] = 0.f; p[15] = 0.f;
    if (gid < NLB) {
      int idx = 0;
#pragma unroll
      for (int c = 0; c < NC; ++c) {
        p[c] = onehot[(size_t)gid * NC + c];
        if (p[c] == 1.0f) idx = c;
      }
      atomicAdd(&lcnt[idx], 1.0f);
    } else {
      int r = (gid < NLB + NULB) ? (gid - NLB) : (gid - NLB - NULB);
      bool count = (gid < NLB + NULB);
      float a[NC], bb[NC];
#pragma unroll
      for (int c = 0; c < NC; ++c) { a[c] = l1[(size_t)r * NC + c]; bb[c] = l2[(size_t)r * NC + c]; }
      float m1 = a[0], m2 = bb[0];
#pragma unroll
      for (int c = 1; c < NC; ++c) { m1 = fmaxf(m1, a[c]); m2 = fmaxf(m2, bb[c]); }
      float s1 = 0.0f, s2 = 0.0f;
#pragma unroll
      for (int c = 0; c < NC; ++c) {
        s1 += expf(2.0f * (a[c] - m1));
        s2 += expf(2.0f * (bb[c] - m2));
      }
      bool take1 = (s1 <= s2);  // max(prob1)=1/s1 >= 1/s2=max(prob2)
      float g[NC];
#pragma unroll
      for (int c = 0; c < NC; ++c) g[c] = take1 ? a[c] : bb[c];
      float mg = g[0];
#pragma unroll
      for (int c = 1; c < NC; ++c) mg = fmaxf(mg, g[c]);
      float e[NC]; float sg = 0.0f;
#pragma unroll
      for (int c = 0; c < NC; ++c) { e[c] = expf(g[c] - mg); sg += e[c]; }
      float msk[NC];
#pragma unroll
      for (int c = 0; c < NC; ++c) msk[c] = ((e[c] / sg) >= 0.95f) ? g[c] : 0.0f;
      float mx = msk[0]; int mi = 0;
#pragma unroll
      for (int c = 1; c < NC; ++c) if (msk[c] > mx) { mx = msk[c]; mi = c; }
      if (count && mx != 0.0f) atomicAdd(&lcnt[mi], 2.0f);
      float mm = 2.0f * msk[0];
#pragma unroll
      for (int c = 1; c < NC; ++c) mm = fmaxf(mm, 2.0f * msk[c]);
      float q[NC]; float sp = 0.0f;
#pragma unroll
      for (int c = 0; c < NC; ++c) { q[c] = expf(2.0f * msk[c] - mm); sp += q[c]; }
#pragma unroll
      for (int c = 0; c < NC; ++c) p[c] = q[c] / sp;
    }
#pragma unroll
    for (int c = 0; c < 16; ++c) Vtmp[t * 16 + c] = p[c];
  }
  __syncthreads();
  if (t < 16) clsPart[(size_t)vb * 16 + t] = (t < NC) ? lcnt[t] : 0.0f;
  // scatter to VF f16 pair-frag layout: 2 pair-groups x 64 chunks per block
  if (t < 128) {
    int gbase = vb * 2;          // global pair-group base (0..511)
    int G = t >> 6;              // local pair-group 0..1
    int l = t & 63;
    int q = l >> 4;
    int n = l & 15;
    union { f16_t h[8]; uint4 uu; } pk;
#pragma unroll
    for (int d = 0; d < 4; ++d) {
      pk.h[d]     = (f16_t)Vtmp[(G * 32      + q * 4 + d) * 16 + n];
      pk.h[4 + d] = (f16_t)Vtmp[(G * 32 + 16 + q * 4 + d) * 16 + n];
    }
    *(uint4*)(VF + ((size_t)(gbase + G) * 64 + l) * 8) = pk.uu;
  }
}

// ================= attention partials =================
// R17: counted-vmcnt 3-buffer pipeline (T3/T4). The old 2-buffer schedule's
// __syncthreads() drained vmcnt(0) every tile -- at that point the ONLY
// outstanding loads were exactly the tile the next compute needs, so every
// tile round ended in a full drain with all 4 blocks/CU convoy-aligned
// (explains R13-R15: occupancy, depth-2 ILP, setprio all ~neutral while the
// MFMA pipe sits at ~44%). Now: 3 LDS buffers (30720 B), stage depth 2, and
// the pre-compute wait is s_waitcnt vmcnt(6) -- the next TWO tiles' loads
// (3/thread each, made uniform via a duplicate V-load on the upper half)
// stay in flight across raw s_barriers. Never drains to 0 in steady state.
// QK: one mfma_scale_f32_16x16x128_f8f6f4 per 16x16 tile. PV: even/odd
// 16-row chunks paired in one mfma_f32_16x16x32_f16. Depth-2 s-pipeline +
// setprio kept from R15 (neutral, harmless).
#define WAITV(n) asm volatile("s_waitcnt vmcnt(" #n ")" ::: "memory")
__launch_bounds__(256, 4)
__global__ void kattn(const u8* __restrict__ F8, const f16_t* __restrict__ VF,
                      float* __restrict__ Ppart) {
  __shared__ __align__(16) u8 Fs[3][BJ * 128];   // 3 x 8 KB fp8 swizzled tile image
  __shared__ uint4 Vs4[3][128];                  // 3 x 2 KB f16 V pair-frags
  int t = threadIdx.x;
  int lane = t & 63;
  int wave = t >> 6;    // 0..3
  int q = lane >> 4;    // 0..3
  int r = lane & 15;    // 0..15
  int i0 = blockIdx.x * BI + wave * 64;
  int jbase = blockIdx.y * JSEG;

  // stationary B-frags: 4 i-sets, 32 fp8 bytes/lane (chunks 2q, 2q+1 of row)
  i32x8 bfr[4];
#pragma unroll
  for (int s = 0; s < 4; ++s) {
    int row = i0 + s * 16 + r;
    union { uint4 h[2]; i32x8 v; } bb;
    bb.h[0] = *(const uint4*)(F8 + f8idx(row, 2 * q));
    bb.h[1] = *(const uint4*)(F8 + f8idx(row, 2 * q + 1));
    bfr[s] = bb.v;
  }

  f32x4 acc[4];
#pragma unroll
  for (int s = 0; s < 4; ++s) acc[s] = (f32x4){0.f, 0.f, 0.f, 0.f};
  const f32x4 kZero = {0.f, 0.f, 0.f, 0.f};

  // ---- staging: uniform 3 loads per thread (2 F + 1 V) ----
  // j0 is a multiple of 64; the 64-row half of the 128-row F8 macro-tile is
  // contiguous: base = (j0>>7)*16384 + (j0&64)*128. Swizzle is row&7-local and
  // 64-row tiles preserve row&7, so the compute-side chunk XOR is unchanged.
  // V: 128 chunks over 256 threads -> chunk t&127; the upper 128 threads
  // duplicate-write identical data (benign) so every WAVE has exactly 3
  // outstanding loads per stage => counted vmcnt works uniformly.
  auto stage = [&](int buf, int j0) {
    const uint4* srcF = (const uint4*)(F8 + (((size_t)(j0 >> 7)) << 14)
                                          + (((size_t)(j0 & 64)) << 7));
#pragma unroll
    for (int k = 0; k < 2; ++k) {
      int off = (k << 8) + t;   // 16B-chunk idx 0..511, lane-consecutive per wave
      __builtin_amdgcn_global_load_lds(
          (const __attribute__((address_space(1))) uint4*)(srcF + off),
          (__attribute__((address_space(3))) uint4*)((uint4*)Fs[buf] + off), 16, 0, 0);
    }
    int vc = t & 127;
    const uint4* srcV = (const uint4*)VF + ((size_t)(j0 >> 5) << 6);
    __builtin_amdgcn_global_load_lds(
        (const __attribute__((address_space(1))) uint4*)(srcV + vc),
        (__attribute__((address_space(3))) uint4*)(Vs4[buf] + vc), 16, 0, 0);
  };

  auto compute = [&](int buf) {
    const u8* fsb = Fs[buf];
    const uint4* vsb = Vs4[buf];
#pragma unroll
    for (int jp = 0; jp < 2; ++jp) {   // pairs of 16-row j-chunks (64 rows total)
      union { uint4 h[2]; i32x8 v; } afe, afo;
      const u8* re = fsb + (jp * 32 + r) * 128;       // even chunk row
      const u8* ro = re + 16 * 128;                   // odd chunk row
      int c0 = (((2 * q) ^ (r & 7)) & 7) << 4;
      int c1 = (((2 * q + 1) ^ (r & 7)) & 7) << 4;
      afe.h[0] = *(const uint4*)(re + c0);
      afe.h[1] = *(const uint4*)(re + c1);
      afo.h[0] = *(const uint4*)(ro + c0);
      afo.h[1] = *(const uint4*)(ro + c1);
      union { uint4 qd; f16x8 v; } bv;
      bv.qd = vsb[jp * 64 + lane];

      // prologue: QK pair for s=0
      __builtin_amdgcn_s_setprio(1);
      f32x4 ce = __builtin_amdgcn_mfma_scale_f32_16x16x128_f8f6f4(
          afe.v, bfr[0], kZero, 0, 0, 0, 0x7F7F7F7Fu, 0, 0x7F7F7F7Fu);
      f32x4 co = __builtin_amdgcn_mfma_scale_f32_16x16x128_f8f6f4(
          afo.v, bfr[0], kZero, 0, 0, 0, 0x7F7F7F7Fu, 0, 0x7F7F7F7Fu);
      __builtin_amdgcn_s_setprio(0);
#pragma unroll
      for (int s = 0; s < 4; ++s) {
        f32x4 cen, con;
        if (s < 3) {   // issue next QK pair BEFORE consuming this one
          __builtin_amdgcn_s_setprio(1);
          cen = __builtin_amdgcn_mfma_scale_f32_16x16x128_f8f6f4(
              afe.v, bfr[s + 1], kZero, 0, 0, 0, 0x7F7F7F7Fu, 0, 0x7F7F7F7Fu);
          con = __builtin_amdgcn_mfma_scale_f32_16x16x128_f8f6f4(
              afo.v, bfr[s + 1], kZero, 0, 0, 0, 0x7F7F7F7Fu, 0, 0x7F7F7F7Fu);
          __builtin_amdgcn_s_setprio(0);
        }
        union { u32 u[4]; f16x8 v; } pf;
        pf.u[0] = packexp2f16(ce[0], ce[1]);
        pf.u[1] = packexp2f16(ce[2], ce[3]);
        pf.u[2] = packexp2f16(co[0], co[1]);
        pf.u[3] = packexp2f16(co[2], co[3]);
        __builtin_amdgcn_s_setprio(1);
        acc[s] = __builtin_amdgcn_mfma_f32_16x16x32_f16(pf.v, bv.v, acc[s], 0, 0, 0);
        __builtin_amdgcn_s_setprio(0);
        if (s < 3) { ce = cen; co = con; }
      }
    }
  };

  // ---- 3-buffer, depth-2 pipeline with counted vmcnt ----
  // in flight at the pre-compute(jt) wait: stage(jt+1) [3] + stage(jt+2) [3]
  // -> vmcnt(6) retires exactly stage(jt)'s loads. Epilogue: 3 then 0.
  stage(0, jbase);
  stage(1, jbase + BJ);
#pragma unroll
  for (int jt = 0; jt < NTILE; ++jt) {
    if (jt + 2 < NTILE) stage((jt + 2) % 3, jbase + (jt + 2) * BJ);
    if (jt + 2 < NTILE)      { WAITV(6); }
    else if (jt + 1 < NTILE) { WAITV(3); }
    else                     { WAITV(0); }
    __builtin_amdgcn_s_barrier();          // all waves' stage(jt) writes landed
    __builtin_amdgcn_sched_barrier(0);     // keep ds_reads below the barrier
    compute(jt % 3);
    __builtin_amdgcn_sched_barrier(0);     // keep ds_reads above next barrier
    __builtin_amdgcn_s_barrier();          // reads done before buf reuse (no drain)
  }

  // acc[s] lane(q,r) reg rg = partial[row = i0+s*16+q*4+rg][col = r]
  // V cols 11..15 are structurally zero -> the r==11 lane stores exact zeros,
  // keeping the slab's pad column clean for kfinal's float4 accumulation.
  if (r < 12) {
    float* base = Ppart + ((size_t)blockIdx.y * NROWS + (size_t)i0) * VW;
#pragma unroll
    for (int s = 0; s < 4; ++s) {
      float* op = base + (s * 16 + q * 4) * VW + r;
      op[0 * VW] = acc[s][0];
      op[1 * VW] = acc[s][1];
      op[2 * VW] = acc[s][2];
      op[3 * VW] = acc[s][3];
    }
  }
}

// ---------------- finalize: slab reduce + class-count reduce + divides ----------------
// 256 blocks x 64 threads (1 row/thread, full-chip read of the 12.6 MB slab).
// clsPart is 256 partial rows: each lane sums 4 rows, then a 64-lane shuffle.
__global__ void kfinal(float* __restrict__ out, const float* __restrict__ Ppart,
                       const float* __restrict__ clsPart) {
  __shared__ float clsS[16];
  int t = threadIdx.x;   // 0..63, one wave
  const float4* cp = (const float4*)clsPart;  // 256 rows x 4 float4
  float4 c0 = {0.f, 0.f, 0.f, 0.f}, c1 = c0;
  float c2x = 0.f, c2y = 0.f;
#pragma unroll
  for (int k = 0; k < 4; ++k) {
    int rr = t + 64 * k;
    float4 x0 = cp[rr * 4], x1 = cp[rr * 4 + 1], x2 = cp[rr * 4 + 2];
    c0.x += x0.x; c0.y += x0.y; c0.z += x0.z; c0.w += x0.w;
    c1.x += x1.x; c1.y += x1.y; c1.z += x1.z; c1.w += x1.w;
    c2x += x2.x; c2y += x2.y;
  }
#pragma unroll
  for (int off = 32; off >= 1; off >>= 1) {
    c0.x += __shfl_xor(c0.x, off); c0.y += __shfl_xor(c0.y, off);
    c0.z += __shfl_xor(c0.z, off); c0.w += __shfl_xor(c0.w, off);
    c1.x += __shfl_xor(c1.x, off); c1.y += __shfl_xor(c1.y, off);
    c1.z += __shfl_xor(c1.z, off); c1.w += __shfl_xor(c1.w, off);
    c2x += __shfl_xor(c2x, off); c2y += __shfl_xor(c2y, off);
  }
  if (t == 0) {
    *(float4*)&clsS[0] = c0;
    *(float4*)&clsS[4] = c1;
    clsS[8] = c2x; clsS[9] = c2y;
    clsS[10] = 0.f; clsS[11] = 0.f; clsS[12] = 0.f;
    clsS[13] = 0.f; clsS[14] = 0.f; clsS[15] = 0.f;
  }
  __syncthreads();
  float d[NC]; float tot = 0.0f;
#pragma unroll
  for (int c = 0; c < NC; ++c) { d[c] = clsS[c]; tot += d[c]; }

  int row = blockIdx.x * 64 + t;  // 256 blocks x 64
  float4 a0 = {0.f, 0.f, 0.f, 0.f}, a1 = a0, a2 = a0;
#pragma unroll
  for (int s = 0; s < SEG; ++s) {
    const float4* pr = (const float4*)(Ppart + ((size_t)s * NROWS + (size_t)row) * VW);
    float4 x0 = pr[0], x1 = pr[1], x2 = pr[2];
    a0.x += x0.x; a0.y += x0.y; a0.z += x0.z; a0.w += x0.w;
    a1.x += x1.x; a1.y += x1.y; a1.z += x1.z; a1.w += x1.w;
    a2.x += x2.x; a2.y += x2.y; a2.z += x2.z;
  }
  float num[NC] = {a0.x, a0.y, a0.z, a0.w, a1.x, a1.y, a1.z, a1.w, a2.x, a2.y};
  float rs = 1.0f / a2.z;   // col 10 = attention denominator
  float* op = out + (size_t)row * NC;
#pragma unroll
  for (int c = 0; c < NC; ++c) {
    float den = (d[c] == 0.0f) ? tot : d[c];
    op[c] = num[c] * rs / den;
  }
}

extern "C" void kernel_launch(void* const* d_in, const int* in_sizes, int n_in,
                              void* d_out, int out_size, void* d_ws, size_t ws_size,
                              hipStream_t stream) {
  const float* anchor   = (const float*)d_in[0];  // 6144x128
  const float* positive = (const float*)d_in[1];  // 6144x128
  const float* lbfeat   = (const float*)d_in[2];  // 4096x128
  const float* onehot   = (const float*)d_in[3];  // 4096x10
  const float* l1       = (const float*)d_in[4];  // 6144x10
  const float* l2       = (const float*)d_in[5];  // 6144x10
  float* out = (float*)d_out;                     // 16384x10

  char* ws = (char*)d_ws;
  u8*     F8      = (u8*)ws;                                 // 2 MiB fp8 swizzled image
  f16_t*  VF      = (f16_t*)(ws + 2097152);                  // 512 KiB f16 pair-frags
  float*  Ppart   = (float*)(ws + 2097152 + 524288);         // SEG*NROWS*VW*4 = 12 MiB
  float*  clsPart = (float*)(ws + 2097152 + 524288 + (size_t)SEG * NROWS * VW * 4);  // 16 KiB

  kprep2<<<1024 + NVB, 256, 0, stream>>>(lbfeat, anchor, positive, onehot, l1, l2,
                                         F8, VF, clsPart);
  kattn<<<dim3(NROWS / BI, SEG), 256, 0, stream>>>(F8, VF, Ppart);
  kfinal<<<NVB, 64, 0, stream>>>(out, Ppart, clsPart);
}